// Round 4
// baseline (167.869 us; speedup 1.0000x reference)
//
#include <hip/hip_runtime.h>
#include <math.h>

#define BATCH 32
#define CH 256
#define HW 4096
#define KSEL 8
#define EPSV 1e-5f

typedef __attribute__((ext_vector_type(8))) short short8;
typedef __attribute__((ext_vector_type(4))) float f32x4;
typedef unsigned short ushort_t;

__device__ __forceinline__ unsigned short f2bf(float f) {
    unsigned u = __float_as_uint(f);
    unsigned r = u + 0x7fffu + ((u >> 16) & 1u);   // RNE
    return (unsigned short)(r >> 16);
}
__device__ __forceinline__ float bf2f(unsigned short h) {
    return __uint_as_float(((unsigned)h) << 16);
}

__device__ __forceinline__ void gload16(const void* g, void* l) {
    __builtin_amdgcn_global_load_lds((const __attribute__((address_space(1))) void*)g,
                                     (__attribute__((address_space(3))) void*)l, 16, 0, 0);
}

// -------- K1: per-(b,c) sums + fused prescaled bf16 split write --------
// Hn = bf16(x*invn), L2n = bf16(2*(x*invn - Hn)); row stays in registers.
__global__ __launch_bounds__(256) void statsconv_kernel(const float* __restrict__ x,
                                                        float* __restrict__ s,
                                                        float* __restrict__ sq,
                                                        ushort_t* __restrict__ Hn,
                                                        ushort_t* __restrict__ L2n) {
    int bc = blockIdx.x;
    const float4* p4 = (const float4*)(x + (size_t)bc * HW);
    int t = threadIdx.x;
    float4 xv[4];
    float sum = 0.f, ssq = 0.f;
#pragma unroll
    for (int i = 0; i < 4; ++i) {
        xv[i] = p4[t + 256 * i];
        sum += xv[i].x + xv[i].y + xv[i].z + xv[i].w;
        ssq += xv[i].x * xv[i].x + xv[i].y * xv[i].y + xv[i].z * xv[i].z + xv[i].w * xv[i].w;
    }
    for (int off = 32; off; off >>= 1) {
        sum += __shfl_down(sum, off);
        ssq += __shfl_down(ssq, off);
    }
    __shared__ float ls[4], lq[4];
    __shared__ float sinv;
    int wid = t >> 6, lane = t & 63;
    if (lane == 0) { ls[wid] = sum; lq[wid] = ssq; }
    __syncthreads();
    if (t == 0) {
        float S = ls[0] + ls[1] + ls[2] + ls[3];
        float Q = lq[0] + lq[1] + lq[2] + lq[3];
        s[bc] = S;
        sq[bc] = Q;
        sinv = 1.0f / fmaxf(sqrtf(Q), 1e-12f);
    }
    __syncthreads();
    float w = sinv;
    uint2* H2 = (uint2*)(Hn + (size_t)bc * HW);
    uint2* L2 = (uint2*)(L2n + (size_t)bc * HW);
#pragma unroll
    for (int i = 0; i < 4; ++i) {
        float a0 = xv[i].x * w, a1 = xv[i].y * w, a2 = xv[i].z * w, a3 = xv[i].w * w;
        unsigned short h0 = f2bf(a0), h1 = f2bf(a1), h2 = f2bf(a2), h3 = f2bf(a3);
        unsigned short l0 = f2bf(2.0f * (a0 - bf2f(h0)));
        unsigned short l1 = f2bf(2.0f * (a1 - bf2f(h1)));
        unsigned short l2 = f2bf(2.0f * (a2 - bf2f(h2)));
        unsigned short l3 = f2bf(2.0f * (a3 - bf2f(h3)));
        H2[t + 256 * i] = make_uint2((unsigned)h0 | ((unsigned)h1 << 16),
                                     (unsigned)h2 | ((unsigned)h3 << 16));
        L2[t + 256 * i] = make_uint2((unsigned)l0 | ((unsigned)l1 << 16),
                                     (unsigned)l2 | ((unsigned)l3 << 16));
    }
}

// -------- K2: cos partials C = Hn*(Hn + L2n)^T via bf16 MFMA --------
// global_load_lds staging, linear LDS dest + XOR-swizzled global source,
// same XOR on ds_read (rule 21). 128x128 tile, 4 waves x 64x64, KC=64.
__global__ __launch_bounds__(256, 3) void gram_cos(const ushort_t* __restrict__ Hn,
                                                   const ushort_t* __restrict__ L2n,
                                                   float* __restrict__ cosP) {
    int bj = blockIdx.x, bi = blockIdx.y;
    int z = blockIdx.z;               // 0..127
    int b = z >> 2, q = z & 3;        // Q=4
    const int klen = HW / 4;          // 1024
    int kbase = q * klen;

    __shared__ ushort_t Ah[128 * 64];
    __shared__ ushort_t Bh[128 * 64];
    __shared__ ushort_t Bl[128 * 64];

    int t = threadIdx.x, lane = t & 63, w = t >> 6;
    int wr = (w >> 1) * 64, wc = (w & 1) * 64;
    int fr = lane & 15, fg = lane >> 4;

    // staging: per wave-issue, 64 lanes x 16B = 8 rows x 8 granules
    int rl = lane >> 3;               // row within 8-row group (== r&7)
    int sg = lane & 7;                // dest granule slot
    int gsw = sg ^ rl;                // pre-swizzled source granule

    const ushort_t* HA = Hn + ((size_t)b * CH + bi * 128) * HW;
    const ushort_t* HB = Hn + ((size_t)b * CH + bj * 128) * HW;
    const ushort_t* LB = L2n + ((size_t)b * CH + bj * 128) * HW;
    bool diag = (bi == bj);

    f32x4 acc[4][4] = {};

    for (int kb = 0; kb < klen / 64; ++kb) {
        int k0 = kbase + kb * 64;
#pragma unroll
        for (int i = 0; i < 4; ++i) {
            int rg = w * 32 + i * 8;                 // group base row (multiple of 8)
            size_t goff = (size_t)(rg + rl) * HW + k0 + gsw * 8;
            if (!diag) gload16(HA + goff, &Ah[rg * 64]);
            gload16(HB + goff, &Bh[rg * 64]);
            gload16(LB + goff, &Bl[rg * 64]);
        }
        __syncthreads();          // drains DMA (vmcnt) + all waves ready
        const ushort_t* At = diag ? Bh : Ah;
#pragma unroll
        for (int ks = 0; ks < 2; ++ks) {
            short8 af[4], bhf[4], blf[4];
#pragma unroll
            for (int mi = 0; mi < 4; ++mi) {
                int r = wr + mi * 16 + fr;
                int gk = ks * 4 + fg;
                af[mi] = *(const short8*)&At[r * 64 + ((gk ^ (r & 7)) * 8)];
            }
#pragma unroll
            for (int nj = 0; nj < 4; ++nj) {
                int r = wc + nj * 16 + fr;
                int gk = ks * 4 + fg;
                bhf[nj] = *(const short8*)&Bh[r * 64 + ((gk ^ (r & 7)) * 8)];
                blf[nj] = *(const short8*)&Bl[r * 64 + ((gk ^ (r & 7)) * 8)];
            }
#pragma unroll
            for (int mi = 0; mi < 4; ++mi)
#pragma unroll
                for (int nj = 0; nj < 4; ++nj) {
                    acc[mi][nj] = __builtin_amdgcn_mfma_f32_16x16x32_bf16(af[mi], bhf[nj], acc[mi][nj], 0, 0, 0);
                    acc[mi][nj] = __builtin_amdgcn_mfma_f32_16x16x32_bf16(af[mi], blf[nj], acc[mi][nj], 0, 0, 0);
                }
        }
        __syncthreads();          // all reads done before next stage overwrites
    }

    float* Cp = cosP + (size_t)z * CH * CH;
#pragma unroll
    for (int mi = 0; mi < 4; ++mi)
#pragma unroll
        for (int nj = 0; nj < 4; ++nj) {
#pragma unroll
            for (int reg = 0; reg < 4; ++reg) {
                int r = bi * 128 + wr + mi * 16 + fg * 4 + reg;
                int c = bj * 128 + wc + nj * 16 + fr;
                Cp[(size_t)r * CH + c] = acc[mi][nj][reg];
            }
        }
}

// ------- K3: sum partials over p-chunk + symmetrize (LDS transpose) -------
__global__ __launch_bounds__(256) void reduce_sym(const float* __restrict__ cosP,
                                                  float* __restrict__ symP) {
    int J = blockIdx.x, I = blockIdx.y, zc = blockIdx.z;  // zc 0..7
    const int chunk = 16;                                 // 128 partials / 8
    __shared__ float Tt[64][65];
    int t = threadIdx.x;
    int c = t >> 2, d0 = (t & 3) * 16;
    float acc[16] = {};
    for (int p = zc * chunk; p < (zc + 1) * chunk; ++p) {
        const float* Cp = cosP + (size_t)p * CH * CH;
        float4 t1[4], t2[4];
#pragma unroll
        for (int j4 = 0; j4 < 4; ++j4) {
            t1[j4] = *(const float4*)&Cp[(size_t)(I * 64 + c) * CH + J * 64 + d0 + j4 * 4];
            t2[j4] = *(const float4*)&Cp[(size_t)(J * 64 + c) * CH + I * 64 + d0 + j4 * 4];
        }
        __syncthreads();
#pragma unroll
        for (int j4 = 0; j4 < 4; ++j4) {
            Tt[c][d0 + j4 * 4 + 0] = t2[j4].x;
            Tt[c][d0 + j4 * 4 + 1] = t2[j4].y;
            Tt[c][d0 + j4 * 4 + 2] = t2[j4].z;
            Tt[c][d0 + j4 * 4 + 3] = t2[j4].w;
        }
        __syncthreads();
        const float* t1f = (const float*)t1;
#pragma unroll
        for (int j = 0; j < 16; ++j)
            acc[j] += t1f[j] + Tt[d0 + j][c];
    }
    float* op = symP + (size_t)zc * CH * CH;
#pragma unroll
    for (int j4 = 0; j4 < 4; ++j4) {
        float4 o;
        o.x = acc[j4 * 4 + 0]; o.y = acc[j4 * 4 + 1];
        o.z = acc[j4 * 4 + 2]; o.w = acc[j4 * 4 + 3];
        *(float4*)&op[(size_t)(I * 64 + c) * CH + J * 64 + d0 + j4 * 4] = o;
    }
}

// ---------------- K4: top-8 smallest |cos| per column ----------------
__global__ __launch_bounds__(256) void topk_kernel(const float* __restrict__ symP,
                                                   int* __restrict__ idx) {
    int c = blockIdx.x;
    int d = threadIdx.x;
    float v = 0.f;
#pragma unroll
    for (int zc = 0; zc < 8; ++zc)
        v += symP[(size_t)zc * CH * CH + (size_t)c * CH + d];
    v = fabsf(v * (0.5f / BATCH));

    __shared__ unsigned long long keys[CH];
    __shared__ unsigned long long wmin[4];
    __shared__ unsigned long long bmin;

    keys[d] = ((unsigned long long)__float_as_uint(v) << 32) | (unsigned)d;
    __syncthreads();

    for (int i = 0; i < KSEL; ++i) {
        unsigned long long k = keys[d];
        for (int off = 32; off; off >>= 1) {
            unsigned long long o = __shfl_down(k, off);
            k = (o < k) ? o : k;
        }
        if ((d & 63) == 0) wmin[d >> 6] = k;
        __syncthreads();
        if (d == 0) {
            unsigned long long m = wmin[0];
            if (wmin[1] < m) m = wmin[1];
            if (wmin[2] < m) m = wmin[2];
            if (wmin[3] < m) m = wmin[3];
            bmin = m;
            idx[c * KSEL + i] = (int)(m & 0xffffffffu);
        }
        __syncthreads();
        int sel = (int)(bmin & 0xffffffffu);
        if (d == sel) keys[d] = 0xffffffffffffffffULL;
        __syncthreads();
    }
}

// ---------------- K5: gathered group statistics ----------------
__global__ __launch_bounds__(256) void groupstat_kernel(const float* __restrict__ s,
                                                        const float* __restrict__ sq,
                                                        const int* __restrict__ idx,
                                                        float* __restrict__ mean,
                                                        float* __restrict__ inv) {
    int b = blockIdx.x, c = threadIdx.x;
    float gs = s[b * CH + c], gq = sq[b * CH + c];
#pragma unroll
    for (int i = 1; i < KSEL; ++i) {
        int d = idx[c * KSEL + i];
        gs += s[b * CH + d];
        gq += sq[b * CH + d];
    }
    const float Ninv = 1.0f / (float)(KSEL * HW);
    float m = gs * Ninv;
    float var = gq * Ninv - m * m;
    mean[b * CH + c] = m;
    inv[b * CH + c]  = rsqrtf(var + EPSV);
}

// ---------------- K6: normalize ----------------
__global__ __launch_bounds__(256) void norm_kernel(const float* __restrict__ x,
                                                   const float* __restrict__ mean,
                                                   const float* __restrict__ inv,
                                                   const float* __restrict__ gamma,
                                                   const float* __restrict__ beta,
                                                   float* __restrict__ out) {
    int i = blockIdx.x * 256 + threadIdx.x;
    int bc = i >> 10;
    int c  = bc & (CH - 1);
    float m = mean[bc], v = inv[bc];
    float g  = gamma[c] * v;
    float bt = beta[c] - m * g;
    float4 xv = ((const float4*)x)[i];
    float4 o;
    o.x = xv.x * g + bt;
    o.y = xv.y * g + bt;
    o.z = xv.z * g + bt;
    o.w = xv.w * g + bt;
    ((float4*)out)[i] = o;
}

extern "C" void kernel_launch(void* const* d_in, const int* in_sizes, int n_in,
                              void* d_out, int out_size, void* d_ws, size_t ws_size,
                              hipStream_t stream) {
    const float* x     = (const float*)d_in[0];
    const float* gamma = (const float*)d_in[1];
    const float* beta  = (const float*)d_in[2];
    float* out = (float*)d_out;

    // cosP partials (128 x 256KB = 33.5 MB) live in d_out (134 MB),
    // overwritten by norm_kernel at the end.
    float* cosP = (float*)d_out;

    // ws: Hn(64MB bf16) + L2n(64MB) + symP(2MB) + s/sq/mean/inv + idx = 136.45 MB
    ushort_t* Hn  = (ushort_t*)d_ws;
    ushort_t* L2n = Hn + (size_t)BATCH * CH * HW;
    float* symP = (float*)(L2n + (size_t)BATCH * CH * HW);
    float* s    = symP + (size_t)8 * CH * CH;
    float* sq   = s + BATCH * CH;
    float* mean = sq + BATCH * CH;
    float* inv  = mean + BATCH * CH;
    int*   idx  = (int*)(inv + BATCH * CH);

    statsconv_kernel<<<BATCH * CH, 256, 0, stream>>>(x, s, sq, Hn, L2n);
    gram_cos<<<dim3(2, 2, 128), 256, 0, stream>>>(Hn, L2n, cosP);
    reduce_sym<<<dim3(4, 4, 8), 256, 0, stream>>>(cosP, symP);
    topk_kernel<<<CH, 256, 0, stream>>>(symP, idx);
    groupstat_kernel<<<BATCH, 256, 0, stream>>>(s, sq, idx, mean, inv);
    norm_kernel<<<(BATCH * CH * HW / 4) / 256, 256, 0, stream>>>(x, mean, inv, gamma, beta, out);
}

// Round 5
// 129.053 us; speedup vs baseline: 1.3008x; 1.3008x over previous
//
#include <hip/hip_runtime.h>
#include <math.h>

#define BATCH 32
#define CH 256
#define HW 4096
#define KSEL 8
#define EPSV 1e-5f

typedef __attribute__((ext_vector_type(8))) short short8;
typedef __attribute__((ext_vector_type(4))) float f32x4;

__device__ __forceinline__ unsigned short f2bf(float f) {
    unsigned u = __float_as_uint(f);
    unsigned r = u + 0x7fffu + ((u >> 16) & 1u);   // RNE
    return (unsigned short)(r >> 16);
}
__device__ __forceinline__ float bf2f(unsigned short h) {
    return __uint_as_float(((unsigned)h) << 16);
}

// ---------------- K1: per-(b,c) spatial sums + inverse norms ----------------
__global__ __launch_bounds__(256) void stats_kernel(const float* __restrict__ x,
                                                    float* __restrict__ s,
                                                    float* __restrict__ sq,
                                                    float* __restrict__ invn) {
    int bc = blockIdx.x;
    const float4* p4 = (const float4*)(x + (size_t)bc * HW);
    int t = threadIdx.x;
    float sum = 0.f, ssq = 0.f;
#pragma unroll
    for (int i = 0; i < 4; ++i) {
        float4 v = p4[t + 256 * i];
        sum += v.x + v.y + v.z + v.w;
        ssq += v.x * v.x + v.y * v.y + v.z * v.z + v.w * v.w;
    }
    for (int off = 32; off; off >>= 1) {
        sum += __shfl_down(sum, off);
        ssq += __shfl_down(ssq, off);
    }
    __shared__ float ls[4], lq[4];
    int wid = t >> 6, lane = t & 63;
    if (lane == 0) { ls[wid] = sum; lq[wid] = ssq; }
    __syncthreads();
    if (t == 0) {
        float S = ls[0] + ls[1] + ls[2] + ls[3];
        float Q = lq[0] + lq[1] + lq[2] + lq[3];
        s[bc] = S;
        sq[bc] = Q;
        invn[bc] = 1.0f / fmaxf(sqrtf(Q), 1e-12f);
    }
}

// -------- K2: full 256x256 cos-partial tile per block: C1 = Hn*(Hn+2Ln)^T --------
// 512 threads = 8 waves (2x4), wave tile 128x64, 16x16x32 bf16 MFMA.
// Each x element is read once and converted once per (b,q) block.
// LDS row stride 72 elems (144B): banks rotate 4/row -> <=2-way conflict (free).
__global__ __launch_bounds__(512, 2) void gram256(const float* __restrict__ x,
                                                  const float* __restrict__ invn,
                                                  float* __restrict__ cosP) {
    int z = blockIdx.x;             // 0..255
    int b = z >> 3, q = z & 7;      // Q=8, klen=512
    const float* xb = x + (size_t)b * CH * HW;

    __shared__ unsigned short Hh[CH * 72];
    __shared__ unsigned short Hl[CH * 72];

    int t = threadIdx.x, lane = t & 63, w = t >> 6;
    int wr = (w >> 2) * 128, wc = (w & 3) * 64;
    int fr = lane & 15, fg = lane >> 4;

    // staging: thread covers row rt, 32 cols starting at hf*32
    int rt = t >> 1, hf = t & 1;
    float wsc = invn[b * CH + rt];

    f32x4 acc[8][4] = {};

    for (int kb = 0; kb < 8; ++kb) {
        const float4* src = (const float4*)(xb + (size_t)rt * HW + q * 512 + kb * 64 + hf * 32);
        float4 f[8];
#pragma unroll
        for (int i = 0; i < 8; ++i) f[i] = src[i];
        __syncthreads();           // previous chunk's fragment reads done
#pragma unroll
        for (int p = 0; p < 4; ++p) {
            float a[8];
            a[0] = f[2 * p].x * wsc;     a[1] = f[2 * p].y * wsc;
            a[2] = f[2 * p].z * wsc;     a[3] = f[2 * p].w * wsc;
            a[4] = f[2 * p + 1].x * wsc; a[5] = f[2 * p + 1].y * wsc;
            a[6] = f[2 * p + 1].z * wsc; a[7] = f[2 * p + 1].w * wsc;
            short8 hv, lv;
#pragma unroll
            for (int j = 0; j < 8; ++j) {
                unsigned short h = f2bf(a[j]);
                hv[j] = (short)h;
                lv[j] = (short)f2bf(2.0f * (a[j] - bf2f(h)));
            }
            int addr = rt * 72 + (hf * 4 + p) * 8;
            *(short8*)&Hh[addr] = hv;
            *(short8*)&Hl[addr] = lv;
        }
        __syncthreads();           // tile ready
#pragma unroll
        for (int ks = 0; ks < 2; ++ks) {
            int gk = ks * 4 + fg;
            short8 af[8], bh[4], bl[4];
#pragma unroll
            for (int mi = 0; mi < 8; ++mi)
                af[mi] = *(const short8*)&Hh[(wr + mi * 16 + fr) * 72 + gk * 8];
#pragma unroll
            for (int nj = 0; nj < 4; ++nj) {
                int rb = (wc + nj * 16 + fr) * 72 + gk * 8;
                bh[nj] = *(const short8*)&Hh[rb];
                bl[nj] = *(const short8*)&Hl[rb];
            }
#pragma unroll
            for (int mi = 0; mi < 8; ++mi)
#pragma unroll
                for (int nj = 0; nj < 4; ++nj) {
                    acc[mi][nj] = __builtin_amdgcn_mfma_f32_16x16x32_bf16(af[mi], bh[nj], acc[mi][nj], 0, 0, 0);
                    acc[mi][nj] = __builtin_amdgcn_mfma_f32_16x16x32_bf16(af[mi], bl[nj], acc[mi][nj], 0, 0, 0);
                }
        }
    }

    float* Cp = cosP + (size_t)z * CH * CH;
#pragma unroll
    for (int mi = 0; mi < 8; ++mi)
#pragma unroll
        for (int nj = 0; nj < 4; ++nj) {
#pragma unroll
            for (int reg = 0; reg < 4; ++reg) {
                int r = wr + mi * 16 + fg * 4 + reg;
                int c = wc + nj * 16 + fr;
                Cp[(size_t)r * CH + c] = acc[mi][nj][reg];
            }
        }
}

// ---------------- K3: sum the 256 partials -> R[256][256] ----------------
__global__ __launch_bounds__(1024) void reduceP(const float* __restrict__ cosP,
                                                float* __restrict__ R) {
    int r = blockIdx.x;
    int t = threadIdx.x;
    int d = t & 255, pg = t >> 8;          // 4 p-groups of 64
    const float* base = cosP + (size_t)r * CH + d;
    float a0 = 0.f, a1 = 0.f, a2 = 0.f, a3 = 0.f;
    for (int p = pg * 64; p < pg * 64 + 64; p += 4) {
        a0 += base[(size_t)p * (CH * CH)];
        a1 += base[(size_t)(p + 1) * (CH * CH)];
        a2 += base[(size_t)(p + 2) * (CH * CH)];
        a3 += base[(size_t)(p + 3) * (CH * CH)];
    }
    __shared__ float red[1024];
    red[t] = a0 + a1 + a2 + a3;
    __syncthreads();
    if (t < 256)
        R[(size_t)r * CH + t] = red[t] + red[t + 256] + red[t + 512] + red[t + 768];
}

// -------- K4: symmetrize (R + R^T) + top-8 smallest |cos| per column --------
__global__ __launch_bounds__(256) void symtopk(const float* __restrict__ R,
                                               int* __restrict__ idx) {
    int c = blockIdx.x;
    int d = threadIdx.x;
    float v = fabsf((R[(size_t)c * CH + d] + R[(size_t)d * CH + c]) * (0.5f / BATCH));

    __shared__ unsigned long long keys[CH];
    __shared__ unsigned long long wmin[4];
    __shared__ unsigned long long bmin;

    keys[d] = ((unsigned long long)__float_as_uint(v) << 32) | (unsigned)d;
    __syncthreads();

    for (int i = 0; i < KSEL; ++i) {
        unsigned long long k = keys[d];
        for (int off = 32; off; off >>= 1) {
            unsigned long long o = __shfl_down(k, off);
            k = (o < k) ? o : k;
        }
        if ((d & 63) == 0) wmin[d >> 6] = k;
        __syncthreads();
        if (d == 0) {
            unsigned long long m = wmin[0];
            if (wmin[1] < m) m = wmin[1];
            if (wmin[2] < m) m = wmin[2];
            if (wmin[3] < m) m = wmin[3];
            bmin = m;
            idx[c * KSEL + i] = (int)(m & 0xffffffffu);
        }
        __syncthreads();
        int sel = (int)(bmin & 0xffffffffu);
        if (d == sel) keys[d] = 0xffffffffffffffffULL;
        __syncthreads();
    }
}

// ---------------- K5: gathered group statistics ----------------
__global__ __launch_bounds__(256) void groupstat_kernel(const float* __restrict__ s,
                                                        const float* __restrict__ sq,
                                                        const int* __restrict__ idx,
                                                        float* __restrict__ mean,
                                                        float* __restrict__ inv) {
    int b = blockIdx.x, c = threadIdx.x;
    float gs = s[b * CH + c], gq = sq[b * CH + c];
#pragma unroll
    for (int i = 1; i < KSEL; ++i) {
        int d = idx[c * KSEL + i];
        gs += s[b * CH + d];
        gq += sq[b * CH + d];
    }
    const float Ninv = 1.0f / (float)(KSEL * HW);
    float m = gs * Ninv;
    float var = gq * Ninv - m * m;
    mean[b * CH + c] = m;
    inv[b * CH + c]  = rsqrtf(var + EPSV);
}

// ---------------- K6: normalize ----------------
__global__ __launch_bounds__(256) void norm_kernel(const float* __restrict__ x,
                                                   const float* __restrict__ mean,
                                                   const float* __restrict__ inv,
                                                   const float* __restrict__ gamma,
                                                   const float* __restrict__ beta,
                                                   float* __restrict__ out) {
    int i = blockIdx.x * 256 + threadIdx.x;
    int bc = i >> 10;
    int c  = bc & (CH - 1);
    float m = mean[bc], v = inv[bc];
    float g  = gamma[c] * v;
    float bt = beta[c] - m * g;
    float4 xv = ((const float4*)x)[i];
    float4 o;
    o.x = xv.x * g + bt;
    o.y = xv.y * g + bt;
    o.z = xv.z * g + bt;
    o.w = xv.w * g + bt;
    ((float4*)out)[i] = o;
}

extern "C" void kernel_launch(void* const* d_in, const int* in_sizes, int n_in,
                              void* d_out, int out_size, void* d_ws, size_t ws_size,
                              hipStream_t stream) {
    const float* x     = (const float*)d_in[0];
    const float* gamma = (const float*)d_in[1];
    const float* beta  = (const float*)d_in[2];
    float* out = (float*)d_out;

    // cos partials (256 x 256KB = 64 MB) live in d_out (134 MB); norm_kernel
    // overwrites every byte of d_out at the end.
    float* cosP = (float*)d_out;

    // ws: small arrays only
    float* ws   = (float*)d_ws;
    float* s    = ws;
    float* sq   = s + BATCH * CH;
    float* invn = sq + BATCH * CH;
    float* mean = invn + BATCH * CH;
    float* inv  = mean + BATCH * CH;
    float* R    = inv + BATCH * CH;          // 256*256
    int*   idx  = (int*)(R + CH * CH);       // 256*8

    stats_kernel<<<BATCH * CH, 256, 0, stream>>>(x, s, sq, invn);
    gram256<<<256, 512, 0, stream>>>(x, invn, cosP);
    reduceP<<<CH, 1024, 0, stream>>>(cosP, R);
    symtopk<<<CH, 256, 0, stream>>>(R, idx);
    groupstat_kernel<<<BATCH, 256, 0, stream>>>(s, sq, idx, mean, inv);
    norm_kernel<<<(BATCH * CH * HW / 4) / 256, 256, 0, stream>>>(x, mean, inv, gamma, beta, out);
}

// Round 6
// 118.737 us; speedup vs baseline: 1.4138x; 1.0869x over previous
//
#include <hip/hip_runtime.h>
#include <math.h>

#define BATCH 32
#define CH 256
#define HW 4096
#define KSEL 8
#define EPSV 1e-5f

typedef __attribute__((ext_vector_type(8))) short short8;
typedef __attribute__((ext_vector_type(4))) float f32x4;

__device__ __forceinline__ unsigned short f2bf(float f) {
    unsigned u = __float_as_uint(f);
    unsigned r = u + 0x7fffu + ((u >> 16) & 1u);   // RNE
    return (unsigned short)(r >> 16);
}
__device__ __forceinline__ float bf2f(unsigned short h) {
    return __uint_as_float(((unsigned)h) << 16);
}

// ---- K1: raw-x Gram partials (256x256 per (b,q)) + fused s/sq partials ----
// 512 threads = 8 waves (2x4), wave tile 128x64, bf16 16x16x32 MFMA,
// C1 = H*(H + 2L)^T trick (drops only the L*L^T term, ~1e-7 relative).
// LDS row stride 72 elems (144B): bank rotation 4/row -> <=2-way conflict.
__global__ __launch_bounds__(512, 2) void gram256(const float* __restrict__ x,
                                                  float* __restrict__ cosP,
                                                  float* __restrict__ sP,
                                                  float* __restrict__ sqP) {
    int z = blockIdx.x;             // 0..255
    int b = z >> 3, q = z & 7;      // Q=8, klen=512
    const float* xb = x + (size_t)b * CH * HW;

    __shared__ unsigned short Hh[CH * 72];
    __shared__ unsigned short Hl[CH * 72];

    int t = threadIdx.x, lane = t & 63, w = t >> 6;
    int wr = (w >> 2) * 128, wc = (w & 3) * 64;
    int fr = lane & 15, fg = lane >> 4;

    // staging: thread covers row rt, 32 cols starting at hf*32 of each 64-chunk
    int rt = t >> 1, hf = t & 1;

    float sl = 0.f, sql = 0.f;
    f32x4 acc[8][4] = {};

    for (int kb = 0; kb < 8; ++kb) {
        const float4* src = (const float4*)(xb + (size_t)rt * HW + q * 512 + kb * 64 + hf * 32);
        float4 f[8];
#pragma unroll
        for (int i = 0; i < 8; ++i) f[i] = src[i];
        __syncthreads();           // previous chunk's fragment reads done
#pragma unroll
        for (int p = 0; p < 4; ++p) {
            float a[8];
            a[0] = f[2 * p].x;     a[1] = f[2 * p].y;
            a[2] = f[2 * p].z;     a[3] = f[2 * p].w;
            a[4] = f[2 * p + 1].x; a[5] = f[2 * p + 1].y;
            a[6] = f[2 * p + 1].z; a[7] = f[2 * p + 1].w;
            short8 hv, lv;
#pragma unroll
            for (int j = 0; j < 8; ++j) {
                sl += a[j];
                sql += a[j] * a[j];
                unsigned short h = f2bf(a[j]);
                hv[j] = (short)h;
                lv[j] = (short)f2bf(2.0f * (a[j] - bf2f(h)));
            }
            int addr = rt * 72 + (hf * 4 + p) * 8;
            *(short8*)&Hh[addr] = hv;
            *(short8*)&Hl[addr] = lv;
        }
        __syncthreads();           // tile ready
#pragma unroll
        for (int ks = 0; ks < 2; ++ks) {
            int gk = ks * 4 + fg;
            short8 af[8], bh[4], bl[4];
#pragma unroll
            for (int mi = 0; mi < 8; ++mi)
                af[mi] = *(const short8*)&Hh[(wr + mi * 16 + fr) * 72 + gk * 8];
#pragma unroll
            for (int nj = 0; nj < 4; ++nj) {
                int rb = (wc + nj * 16 + fr) * 72 + gk * 8;
                bh[nj] = *(const short8*)&Hh[rb];
                bl[nj] = *(const short8*)&Hl[rb];
            }
#pragma unroll
            for (int mi = 0; mi < 8; ++mi)
#pragma unroll
                for (int nj = 0; nj < 4; ++nj) {
                    acc[mi][nj] = __builtin_amdgcn_mfma_f32_16x16x32_bf16(af[mi], bh[nj], acc[mi][nj], 0, 0, 0);
                    acc[mi][nj] = __builtin_amdgcn_mfma_f32_16x16x32_bf16(af[mi], bl[nj], acc[mi][nj], 0, 0, 0);
                }
        }
    }

    // s/sq partials: combine the two half-row threads (adjacent lanes)
    sl += __shfl_down(sl, 1);
    sql += __shfl_down(sql, 1);
    if (hf == 0) {
        sP[(size_t)z * CH + rt] = sl;
        sqP[(size_t)z * CH + rt] = sql;
    }

    float* Cp = cosP + (size_t)z * CH * CH;
#pragma unroll
    for (int mi = 0; mi < 8; ++mi)
#pragma unroll
        for (int nj = 0; nj < 4; ++nj) {
#pragma unroll
            for (int reg = 0; reg < 4; ++reg) {
                int r = wr + mi * 16 + fg * 4 + reg;
                int c = wc + nj * 16 + fr;
                Cp[(size_t)r * CH + c] = acc[mi][nj][reg];
            }
        }
}

// ---- K2: finalize per-(b,c) stats from the 8 q-partials ----
__global__ __launch_bounds__(256) void finalize_kernel(const float* __restrict__ sP,
                                                       const float* __restrict__ sqP,
                                                       float* __restrict__ s,
                                                       float* __restrict__ sq,
                                                       float* __restrict__ invn) {
    int b = blockIdx.x, c = threadIdx.x;
    float S = 0.f, Q = 0.f;
#pragma unroll
    for (int q = 0; q < 8; ++q) {
        S += sP[(size_t)(b * 8 + q) * CH + c];
        Q += sqP[(size_t)(b * 8 + q) * CH + c];
    }
    s[b * CH + c] = S;
    sq[b * CH + c] = Q;
    invn[b * CH + c] = 1.0f / fmaxf(sqrtf(Q), 1e-12f);
}

// ---- K3: weighted sum of partials -> R[256][256] (invn applied per batch) ----
__global__ __launch_bounds__(1024) void reduceP(const float* __restrict__ cosP,
                                                const float* __restrict__ invn,
                                                float* __restrict__ R) {
    int r = blockIdx.x;
    int t = threadIdx.x;
    int d = t & 255, pg = t >> 8;          // 4 groups of 8 batches
    const float* base = cosP + (size_t)r * CH + d;
    float acc = 0.f;
    for (int b = pg * 8; b < pg * 8 + 8; ++b) {
        float part = 0.f;
#pragma unroll
        for (int q = 0; q < 8; ++q)
            part += base[(size_t)(b * 8 + q) * (CH * CH)];
        acc += part * invn[b * CH + d] * invn[b * CH + r];
    }
    __shared__ float red[1024];
    red[t] = acc;
    __syncthreads();
    if (t < 256)
        R[(size_t)r * CH + t] = red[t] + red[t + 256] + red[t + 512] + red[t + 768];
}

// -------- K4: symmetrize (R + R^T) + top-8 smallest |cos| per column --------
__global__ __launch_bounds__(256) void symtopk(const float* __restrict__ R,
                                               int* __restrict__ idx) {
    int c = blockIdx.x;
    int d = threadIdx.x;
    float v = fabsf((R[(size_t)c * CH + d] + R[(size_t)d * CH + c]) * (0.5f / BATCH));

    __shared__ unsigned long long keys[CH];
    __shared__ unsigned long long wmin[4];
    __shared__ unsigned long long bmin;

    keys[d] = ((unsigned long long)__float_as_uint(v) << 32) | (unsigned)d;
    __syncthreads();

    for (int i = 0; i < KSEL; ++i) {
        unsigned long long k = keys[d];
        for (int off = 32; off; off >>= 1) {
            unsigned long long o = __shfl_down(k, off);
            k = (o < k) ? o : k;
        }
        if ((d & 63) == 0) wmin[d >> 6] = k;
        __syncthreads();
        if (d == 0) {
            unsigned long long m = wmin[0];
            if (wmin[1] < m) m = wmin[1];
            if (wmin[2] < m) m = wmin[2];
            if (wmin[3] < m) m = wmin[3];
            bmin = m;
            idx[c * KSEL + i] = (int)(m & 0xffffffffu);
        }
        __syncthreads();
        int sel = (int)(bmin & 0xffffffffu);
        if (d == sel) keys[d] = 0xffffffffffffffffULL;
        __syncthreads();
    }
}

// ---------------- K5: gathered group statistics ----------------
__global__ __launch_bounds__(256) void groupstat_kernel(const float* __restrict__ s,
                                                        const float* __restrict__ sq,
                                                        const int* __restrict__ idx,
                                                        float* __restrict__ mean,
                                                        float* __restrict__ inv) {
    int b = blockIdx.x, c = threadIdx.x;
    float gs = s[b * CH + c], gq = sq[b * CH + c];
#pragma unroll
    for (int i = 1; i < KSEL; ++i) {
        int d = idx[c * KSEL + i];
        gs += s[b * CH + d];
        gq += sq[b * CH + d];
    }
    const float Ninv = 1.0f / (float)(KSEL * HW);
    float m = gs * Ninv;
    float var = gq * Ninv - m * m;
    mean[b * CH + c] = m;
    inv[b * CH + c]  = rsqrtf(var + EPSV);
}

// ---------------- K6: normalize ----------------
__global__ __launch_bounds__(256) void norm_kernel(const float* __restrict__ x,
                                                   const float* __restrict__ mean,
                                                   const float* __restrict__ inv,
                                                   const float* __restrict__ gamma,
                                                   const float* __restrict__ beta,
                                                   float* __restrict__ out) {
    int i = blockIdx.x * 256 + threadIdx.x;
    int bc = i >> 10;
    int c  = bc & (CH - 1);
    float m = mean[bc], v = inv[bc];
    float g  = gamma[c] * v;
    float bt = beta[c] - m * g;
    float4 xv = ((const float4*)x)[i];
    float4 o;
    o.x = xv.x * g + bt;
    o.y = xv.y * g + bt;
    o.z = xv.z * g + bt;
    o.w = xv.w * g + bt;
    ((float4*)out)[i] = o;
}

extern "C" void kernel_launch(void* const* d_in, const int* in_sizes, int n_in,
                              void* d_out, int out_size, void* d_ws, size_t ws_size,
                              hipStream_t stream) {
    const float* x     = (const float*)d_in[0];
    const float* gamma = (const float*)d_in[1];
    const float* beta  = (const float*)d_in[2];
    float* out = (float*)d_out;

    // Gram partials (256 x 256KB = 64 MB) live in d_out (134 MB); norm_kernel
    // overwrites every byte of d_out at the end.
    float* cosP = (float*)d_out;

    // ws: small arrays only
    float* ws   = (float*)d_ws;
    float* sP   = ws;                         // 256*256 partial s
    float* sqP  = sP + 256 * CH;              // 256*256 partial sq
    float* s    = sqP + 256 * CH;
    float* sq   = s + BATCH * CH;
    float* invn = sq + BATCH * CH;
    float* mean = invn + BATCH * CH;
    float* inv  = mean + BATCH * CH;
    float* R    = inv + BATCH * CH;           // 256*256
    int*   idx  = (int*)(R + CH * CH);        // 256*8

    gram256<<<256, 512, 0, stream>>>(x, cosP, sP, sqP);
    finalize_kernel<<<BATCH, 256, 0, stream>>>(sP, sqP, s, sq, invn);
    reduceP<<<CH, 1024, 0, stream>>>(cosP, invn, R);
    symtopk<<<CH, 256, 0, stream>>>(R, idx);
    groupstat_kernel<<<BATCH, 256, 0, stream>>>(s, sq, idx, mean, inv);
    norm_kernel<<<(BATCH * CH * HW / 4) / 256, 256, 0, stream>>>(x, mean, inv, gamma, beta, out);
}

// Round 7
// 110.949 us; speedup vs baseline: 1.5130x; 1.0702x over previous
//
#include <hip/hip_runtime.h>
#include <math.h>

#define BATCH 32
#define CH 256
#define HW 4096
#define KSEL 8
#define EPSV 1e-5f

typedef __attribute__((ext_vector_type(8))) short short8;
typedef __attribute__((ext_vector_type(4))) float f32x4;

__device__ __forceinline__ unsigned short f2bf(float f) {
    unsigned u = __float_as_uint(f);
    unsigned r = u + 0x7fffu + ((u >> 16) & 1u);   // RNE
    return (unsigned short)(r >> 16);
}
__device__ __forceinline__ float bf2f(unsigned short h) {
    return __uint_as_float(((unsigned)h) << 16);
}

// ---- K1: raw-x Gram partials (256x256 per (b,q)) + fused s/sq partials ----
// 512 threads = 8 waves (2x4), wave tile 128x64, bf16 16x16x32 MFMA,
// C1 = H*(H + 2L)^T trick (drops only the L*L^T term, ~1e-7 relative).
// LDS: XOR-granule layout row*64 + ((g ^ (row&7))*8) — 0 conflicts (R3/R4).
// Pipeline: convert(kb)->LDS, ISSUE loads(kb+1), barrier, MFMA(kb)  [T14]
__global__ __launch_bounds__(512, 1) void gram256(const float* __restrict__ x,
                                                  float* __restrict__ cosP,
                                                  float* __restrict__ sP,
                                                  float* __restrict__ sqP) {
    int z = blockIdx.x;             // 0..255
    int b = z >> 3, q = z & 7;      // Q=8, klen=512
    const float* xb = x + (size_t)b * CH * HW;

    __shared__ unsigned short Hh[CH * 64];
    __shared__ unsigned short Hl[CH * 64];

    int t = threadIdx.x, lane = t & 63, w = t >> 6;
    int wr = (w >> 2) * 128, wc = (w & 3) * 64;
    int fr = lane & 15, fg = lane >> 4;

    // staging: thread covers row rt, 32 cols starting at hf*32 of each 64-chunk
    int rt = t >> 1, hf = t & 1;
    const float4* srcbase = (const float4*)(xb + (size_t)rt * HW + q * 512 + hf * 32);

    float sl = 0.f, sql = 0.f;
    f32x4 acc[8][4] = {};
    float4 f[8];

    // prologue: load chunk 0
#pragma unroll
    for (int i = 0; i < 8; ++i) f[i] = srcbase[i];

    for (int kb = 0; kb < 8; ++kb) {
        __syncthreads();           // previous chunk's fragment reads done
        // convert current chunk -> LDS (+ stats accumulation)
#pragma unroll
        for (int p = 0; p < 4; ++p) {
            float a[8];
            a[0] = f[2 * p].x;     a[1] = f[2 * p].y;
            a[2] = f[2 * p].z;     a[3] = f[2 * p].w;
            a[4] = f[2 * p + 1].x; a[5] = f[2 * p + 1].y;
            a[6] = f[2 * p + 1].z; a[7] = f[2 * p + 1].w;
            short8 hv, lv;
#pragma unroll
            for (int j = 0; j < 8; ++j) {
                sl += a[j];
                sql += a[j] * a[j];
                unsigned short h = f2bf(a[j]);
                hv[j] = (short)h;
                lv[j] = (short)f2bf(2.0f * (a[j] - bf2f(h)));
            }
            int g = hf * 4 + p;
            int addr = rt * 64 + ((g ^ (rt & 7)) * 8);
            *(short8*)&Hh[addr] = hv;
            *(short8*)&Hl[addr] = lv;
        }
        // issue next chunk's loads NOW (latency hides under MFMA phase)
        if (kb < 7) {
            const float4* src = srcbase + (size_t)(kb + 1) * 16;
#pragma unroll
            for (int i = 0; i < 8; ++i) f[i] = src[i];
        }
        __syncthreads();           // tile ready
#pragma unroll
        for (int ks = 0; ks < 2; ++ks) {
            int gk = ks * 4 + fg;
            short8 af[8], bh[4], bl[4];
#pragma unroll
            for (int mi = 0; mi < 8; ++mi) {
                int r = wr + mi * 16 + fr;
                af[mi] = *(const short8*)&Hh[r * 64 + ((gk ^ (r & 7)) * 8)];
            }
#pragma unroll
            for (int nj = 0; nj < 4; ++nj) {
                int r = wc + nj * 16 + fr;
                int rb = r * 64 + ((gk ^ (r & 7)) * 8);
                bh[nj] = *(const short8*)&Hh[rb];
                bl[nj] = *(const short8*)&Hl[rb];
            }
#pragma unroll
            for (int mi = 0; mi < 8; ++mi)
#pragma unroll
                for (int nj = 0; nj < 4; ++nj) {
                    acc[mi][nj] = __builtin_amdgcn_mfma_f32_16x16x32_bf16(af[mi], bh[nj], acc[mi][nj], 0, 0, 0);
                    acc[mi][nj] = __builtin_amdgcn_mfma_f32_16x16x32_bf16(af[mi], bl[nj], acc[mi][nj], 0, 0, 0);
                }
        }
    }

    // s/sq partials: combine the two half-row threads (adjacent lanes)
    sl += __shfl_down(sl, 1);
    sql += __shfl_down(sql, 1);
    if (hf == 0) {
        sP[(size_t)z * CH + rt] = sl;
        sqP[(size_t)z * CH + rt] = sql;
    }

    float* Cp = cosP + (size_t)z * CH * CH;
#pragma unroll
    for (int mi = 0; mi < 8; ++mi)
#pragma unroll
        for (int nj = 0; nj < 4; ++nj) {
#pragma unroll
            for (int reg = 0; reg < 4; ++reg) {
                int r = wr + mi * 16 + fg * 4 + reg;
                int c = wc + nj * 16 + fr;
                Cp[(size_t)r * CH + c] = acc[mi][nj][reg];
            }
        }
}

// ---- K2: finalize per-(b,c) stats from the 8 q-partials ----
__global__ __launch_bounds__(256) void finalize_kernel(const float* __restrict__ sP,
                                                       const float* __restrict__ sqP,
                                                       float* __restrict__ s,
                                                       float* __restrict__ sq,
                                                       float* __restrict__ invn) {
    int b = blockIdx.x, c = threadIdx.x;
    float S = 0.f, Q = 0.f;
#pragma unroll
    for (int q = 0; q < 8; ++q) {
        S += sP[(size_t)(b * 8 + q) * CH + c];
        Q += sqP[(size_t)(b * 8 + q) * CH + c];
    }
    s[b * CH + c] = S;
    sq[b * CH + c] = Q;
    invn[b * CH + c] = 1.0f / fmaxf(sqrtf(Q), 1e-12f);
}

// ---- K3: weighted sum of partials -> R[256][256] (invn applied per batch) ----
__global__ __launch_bounds__(1024) void reduceP(const float* __restrict__ cosP,
                                                const float* __restrict__ invn,
                                                float* __restrict__ R) {
    int r = blockIdx.x;
    int t = threadIdx.x;
    int d = t & 255, pg = t >> 8;          // 4 groups of 8 batches
    const float* base = cosP + (size_t)r * CH + d;
    float acc = 0.f;
    for (int b = pg * 8; b < pg * 8 + 8; ++b) {
        float part = 0.f;
#pragma unroll
        for (int q = 0; q < 8; ++q)
            part += base[(size_t)(b * 8 + q) * (CH * CH)];
        acc += part * invn[b * CH + d] * invn[b * CH + r];
    }
    __shared__ float red[1024];
    red[t] = acc;
    __syncthreads();
    if (t < 256)
        R[(size_t)r * CH + t] = red[t] + red[t + 256] + red[t + 512] + red[t + 768];
}

// -------- K4: symmetrize (R + R^T) + top-8 smallest |cos| per column --------
__global__ __launch_bounds__(256) void symtopk(const float* __restrict__ R,
                                               int* __restrict__ idx) {
    int c = blockIdx.x;
    int d = threadIdx.x;
    float v = fabsf((R[(size_t)c * CH + d] + R[(size_t)d * CH + c]) * (0.5f / BATCH));

    __shared__ unsigned long long keys[CH];
    __shared__ unsigned long long wmin[4];
    __shared__ unsigned long long bmin;

    keys[d] = ((unsigned long long)__float_as_uint(v) << 32) | (unsigned)d;
    __syncthreads();

    for (int i = 0; i < KSEL; ++i) {
        unsigned long long k = keys[d];
        for (int off = 32; off; off >>= 1) {
            unsigned long long o = __shfl_down(k, off);
            k = (o < k) ? o : k;
        }
        if ((d & 63) == 0) wmin[d >> 6] = k;
        __syncthreads();
        if (d == 0) {
            unsigned long long m = wmin[0];
            if (wmin[1] < m) m = wmin[1];
            if (wmin[2] < m) m = wmin[2];
            if (wmin[3] < m) m = wmin[3];
            bmin = m;
            idx[c * KSEL + i] = (int)(m & 0xffffffffu);
        }
        __syncthreads();
        int sel = (int)(bmin & 0xffffffffu);
        if (d == sel) keys[d] = 0xffffffffffffffffULL;
        __syncthreads();
    }
}

// ---------------- K5: gathered group statistics ----------------
__global__ __launch_bounds__(256) void groupstat_kernel(const float* __restrict__ s,
                                                        const float* __restrict__ sq,
                                                        const int* __restrict__ idx,
                                                        float* __restrict__ mean,
                                                        float* __restrict__ inv) {
    int b = blockIdx.x, c = threadIdx.x;
    float gs = s[b * CH + c], gq = sq[b * CH + c];
#pragma unroll
    for (int i = 1; i < KSEL; ++i) {
        int d = idx[c * KSEL + i];
        gs += s[b * CH + d];
        gq += sq[b * CH + d];
    }
    const float Ninv = 1.0f / (float)(KSEL * HW);
    float m = gs * Ninv;
    float var = gq * Ninv - m * m;
    mean[b * CH + c] = m;
    inv[b * CH + c]  = rsqrtf(var + EPSV);
}

// ---------------- K6: normalize ----------------
__global__ __launch_bounds__(256) void norm_kernel(const float* __restrict__ x,
                                                   const float* __restrict__ mean,
                                                   const float* __restrict__ inv,
                                                   const float* __restrict__ gamma,
                                                   const float* __restrict__ beta,
                                                   float* __restrict__ out) {
    int i = blockIdx.x * 256 + threadIdx.x;
    int bc = i >> 10;
    int c  = bc & (CH - 1);
    float m = mean[bc], v = inv[bc];
    float g  = gamma[c] * v;
    float bt = beta[c] - m * g;
    float4 xv = ((const float4*)x)[i];
    float4 o;
    o.x = xv.x * g + bt;
    o.y = xv.y * g + bt;
    o.z = xv.z * g + bt;
    o.w = xv.w * g + bt;
    ((float4*)out)[i] = o;
}

extern "C" void kernel_launch(void* const* d_in, const int* in_sizes, int n_in,
                              void* d_out, int out_size, void* d_ws, size_t ws_size,
                              hipStream_t stream) {
    const float* x     = (const float*)d_in[0];
    const float* gamma = (const float*)d_in[1];
    const float* beta  = (const float*)d_in[2];
    float* out = (float*)d_out;

    // Gram partials (256 x 256KB = 64 MB) live in d_out (128 MiB); norm_kernel
    // overwrites every byte of d_out at the end.
    float* cosP = (float*)d_out;

    // ws: small arrays only
    float* ws   = (float*)d_ws;
    float* sP   = ws;                         // 256*256 partial s
    float* sqP  = sP + 256 * CH;              // 256*256 partial sq
    float* s    = sqP + 256 * CH;
    float* sq   = s + BATCH * CH;
    float* invn = sq + BATCH * CH;
    float* mean = invn + BATCH * CH;
    float* inv  = mean + BATCH * CH;
    float* R    = inv + BATCH * CH;           // 256*256
    int*   idx  = (int*)(R + CH * CH);        // 256*8

    gram256<<<256, 512, 0, stream>>>(x, cosP, sP, sqP);
    finalize_kernel<<<BATCH, 256, 0, stream>>>(sP, sqP, s, sq, invn);
    reduceP<<<CH, 1024, 0, stream>>>(cosP, invn, R);
    symtopk<<<CH, 256, 0, stream>>>(R, idx);
    groupstat_kernel<<<BATCH, 256, 0, stream>>>(s, sq, idx, mean, inv);
    norm_kernel<<<(BATCH * CH * HW / 4) / 256, 256, 0, stream>>>(x, mean, inv, gamma, beta, out);
}